// Round 7
// baseline (9339.861 us; speedup 1.0000x reference)
//
#include <hip/hip_runtime.h>
#include <hip/hip_bf16.h>

typedef float f32x16 __attribute__((ext_vector_type(16)));

#define DT 0.01f

// sin(x) with Cody-Waite reduction mod pi, accurate to ~2e-7 for |x| < ~6000.
__device__ __forceinline__ float fast_sin(float x) {
  const float INVPI = 0.3183098861837907f;
  float n = rintf(x * INVPI);
  int ni = (int)n;
  float r = fmaf(n, -3.140625f, x);          // n*3.140625 exact for |n| < 2^12
  r = fmaf(n, -9.6765358979e-4f, r);         // pi - 3.140625
  float s = r * r;
  float p = fmaf(s, -2.5052108e-8f, 2.7557319e-6f);
  p = fmaf(s, p, -1.9841270e-4f);
  p = fmaf(s, p, 8.3333333e-3f);
  p = fmaf(s, p, -1.6666667e-1f);
  float res = fmaf(r * s, p, r);             // sin(r), |r| <= pi/2
  return (ni & 1) ? -res : res;              // sin(x) = (-1)^n sin(r)
}

// 4x s_load_dwordx16 from a wave-uniform address + waitcnt, all in one asm
// block. Outputs live in SGPRs; consuming FMAs read them as the free scalar
// operand of v_fmac_f32.
__device__ __forceinline__ void sload4(const float* p, f32x16& a, f32x16& b,
                                       f32x16& c, f32x16& d) {
  asm volatile(
      "s_load_dwordx16 %0, %4, 0\n\t"
      "s_load_dwordx16 %1, %4, 0x40\n\t"
      "s_load_dwordx16 %2, %4, 0x80\n\t"
      "s_load_dwordx16 %3, %4, 0xc0\n\t"
      "s_waitcnt lgkmcnt(0)"
      : "=s"(a), "=s"(b), "=s"(c), "=s"(d)
      : "s"(p));
}

// One 32-float-per-row chunk stage: 8 global_load_lds_dwordx4 per thread,
// zero VGPR cost. LDS dest is linear (wave-uniform base + lane*16B); the
// XOR swizzle e^(r&7) is applied on the GLOBAL source address (rule: swizzle
// both sides or neither — DMA writes linearly, so the source is pre-permuted
// and the compute-side ds_read applies the same XOR). Each wave-call still
// reads 8 full 128B cache lines (permutation stays within each line).
__device__ __forceinline__ void stage_chunk(const float* gsrc, float* lbuf,
                                            int wave) {
#pragma unroll
  for (int k = 0; k < 8; ++k)
    __builtin_amdgcn_global_load_lds(
        (const __attribute__((address_space(1))) unsigned int*)(gsrc + k * 4096),
        (__attribute__((address_space(3))) unsigned int*)(lbuf + k * 1024 + wave * 256),
        16, 0, 0);
}

// Consume one staged chunk: 8 quads x (ds_read_b128 + 4 SGPR-broadcast j) =
// 512 v_fmac_f32 per thread. Swizzled read offset (q^sw) matches the staged
// permutation; start banks cover all 32 banks -> minimal (8/bank) aliasing.
__device__ __forceinline__ void compute_chunk(const float* myrow, int sw, int c,
                                              const float* s2T, float* dot) {
#pragma unroll
  for (int q = 0; q < 8; ++q) {
    const float4 kv = *(const float4*)(myrow + ((q ^ sw) << 2));
    f32x16 sa, sb, sc, sd;
    sload4(s2T + (c * 32 + q * 4) * 16, sa, sb, sc, sd);
#pragma unroll
    for (int b = 0; b < 16; ++b) dot[b] = fmaf(sa[b], kv.x, dot[b]);
#pragma unroll
    for (int b = 0; b < 16; ++b) dot[b] = fmaf(sb[b], kv.y, dot[b]);
#pragma unroll
    for (int b = 0; b < 16; ++b) dot[b] = fmaf(sc[b], kv.z, dot[b]);
#pragma unroll
    for (int b = 0; b < 16; ++b) dot[b] = fmaf(sd[b], kv.w, dot[b]);
  }
}

// K0s[h,j] = sum_m k0[h,m,j]   (k0: [128,512,512])
__global__ __launch_bounds__(256) void kPrep1(const float* __restrict__ k0,
                                              float* __restrict__ K0s) {
  int t = blockIdx.x * 256 + threadIdx.x;     // 65536 threads
  int h = t >> 9, j = t & 511;
  const float* p = k0 + (size_t)h * 262144 + j;
  float s = 0.f;
  for (int m = 0; m < 512; ++m) s += p[(size_t)m * 512];
  K0s[t] = s;
}

// K1s[h,j] = sum_m k1[h,m,j]   (k1: [128,512,128])
__global__ __launch_bounds__(256) void kPrep2(const float* __restrict__ k1,
                                              float* __restrict__ K1s) {
  int t = blockIdx.x * 256 + threadIdx.x;     // 16384 threads
  int h = t >> 7, j = t & 127;
  const float* p = k1 + (size_t)h * 65536 + j;
  float s = 0.f;
  for (int m = 0; m < 512; ++m) s += p[(size_t)m * 128];
  K1s[t] = s;
}

// M[l,j] = sum_h K1s[l,h] * K0s[h,j]   ([128,512] = K1s @ K0s)
__global__ __launch_bounds__(256) void kPrep3(const float* __restrict__ K0s,
                                              const float* __restrict__ K1s,
                                              float* __restrict__ M) {
  int t = blockIdx.x * 256 + threadIdx.x;     // 65536 threads
  int l = t >> 9, j = t & 511;
  float s = 0.f;
#pragma unroll 8
  for (int h = 0; h < 128; ++h) s = fmaf(K1s[l * 128 + h], K0s[h * 512 + j], s);
  M[t] = s;
}

// Kernel A: RK4 bookkeeping + s2T = transpose(M * y_stage).
// Grid 64 WGs x 256: WG = (b = blk>>2, quarter q = blk&3).
// stage: 0 = init (y = y0), 1..4 = RK stages. y ping-pongs on step parity.
__global__ __launch_bounds__(256) void kA(
    const float* __restrict__ y0, const float* __restrict__ bias,
    const float* __restrict__ M, const float* __restrict__ aggp,
    float* __restrict__ ybuf,    // [2][16][512]
    float* __restrict__ racc,    // [16][512]
    float* __restrict__ s2T,     // [128][16]  (j-major, b contiguous)
    float* __restrict__ out,     // [8][16][512]
    int stage, int step) {
  __shared__ float ystage[512];
  __shared__ float red[256];
  const int b = blockIdx.x >> 2, q = blockIdx.x & 3, t = threadIdx.x;
  const float* ycur = ybuf + (step & 1) * 8192;
  float* ynext = ybuf + ((step + 1) & 1) * 8192;

  for (int i = t; i < 512; i += 256) {
    const int idx = b * 512 + i;
    const bool own = (i >> 7) == q;   // this WG owns chunk q of row b
    float ys;
    if (stage == 0) {
      ys = y0[idx];
      if (own) ynext[idx] = ys;       // init writes ybuf[0] (step = -1)
    } else {
      const float r = bias[idx] - (aggp[idx] + aggp[8192 + idx]);
      const float yb = ycur[idx];
      if (stage == 1) {
        ys = fmaf(0.5f * DT, r, yb);
        if (own) racc[idx] = r;
      } else if (stage == 2) {
        ys = fmaf(0.5f * DT, r, yb);
        if (own) racc[idx] = racc[idx] + 2.f * r;
      } else if (stage == 3) {
        ys = fmaf(DT, r, yb);
        if (own) racc[idx] = racc[idx] + 2.f * r;
      } else {  // stage 4: finish step
        ys = yb + (DT / 6.f) * (racc[idx] + r);
        if (own) { ynext[idx] = ys; out[step * 8192 + idx] = ys; }
      }
    }
    ystage[i] = ys;
  }
  __syncthreads();

  // s2[b, l] for l in [q*32, q*32+32): 8 threads per dot, 64 j each.
  const int l = q * 32 + (t >> 3), seg = t & 7;
  const float* Mrow = M + l * 512 + seg * 64;
  float p = 0.f;
#pragma unroll 8
  for (int i = 0; i < 64; ++i) p = fmaf(Mrow[i], ystage[seg * 64 + i], p);
  red[t] = p;
  __syncthreads();
  if (seg == 0) {
    float ssum = 0.f;
#pragma unroll
    for (int k = 0; k < 8; ++k) ssum += red[t + k];
    s2T[l * 16 + b] = ssum;   // transposed: b contiguous per j
  }
}

// Kernel B: one thread per k2 row (l,m). k2 staged via global_load_lds into
// a double-buffered 2x32KB LDS pipeline with counted vmcnt + raw s_barrier
// (NOT __syncthreads — its vmcnt(0) drain would serialize the prefetch).
// Zero staging VGPRs -> no spill (the R5/R6 failure mode). 2 WGs/CU.
__global__ __launch_bounds__(256) void kB(
    const float* __restrict__ k2, const float* __restrict__ adj,
    const float* __restrict__ s2T, float* __restrict__ aggp) {
  __shared__ float lk[2][8192];    // 2 x 32KB chunk buffers (linear [256][32])
  __shared__ float part[64];
  const int t = threadIdx.x;
  const int rid0 = blockIdx.x * 256;
  const int rid = rid0 + t;
  const int l = rid0 >> 9;
  const int half = blockIdx.x & 1;
  const int wave = t >> 6;
  const int sw = t & 7;

  // Per-lane pre-swizzled global base: granule G=k*256+t -> row r=k*32+(t>>3),
  // quad e=t&7; fetch global quad e^(r&7) ( (r&7)==((t>>3)&7), k-independent ).
  const float* gsrc = k2 + (size_t)(rid0 + (t >> 3)) * 128 + ((t & 7) ^ ((t >> 3) & 7)) * 4;

  float dot[16];
#pragma unroll
  for (int b = 0; b < 16; ++b) dot[b] = 0.f;

  stage_chunk(gsrc + 0, lk[0], wave);    // chunk 0 -> buf0
  stage_chunk(gsrc + 32, lk[1], wave);   // chunk 1 -> buf1

  // ---- c = 0 ----
  asm volatile("s_waitcnt vmcnt(8)" ::: "memory");   // chunk 0 landed
  __builtin_amdgcn_s_barrier();
  __builtin_amdgcn_sched_barrier(0);
  compute_chunk(&lk[0][t * 32], sw, 0, s2T, dot);
  __builtin_amdgcn_sched_barrier(0);
  __builtin_amdgcn_s_barrier();                      // buf0 free everywhere
  __builtin_amdgcn_sched_barrier(0);
  stage_chunk(gsrc + 64, lk[0], wave);   // chunk 2 -> buf0

  // ---- c = 1 ----
  asm volatile("s_waitcnt vmcnt(8)" ::: "memory");   // chunk 1 landed
  __builtin_amdgcn_s_barrier();
  __builtin_amdgcn_sched_barrier(0);
  compute_chunk(&lk[1][t * 32], sw, 1, s2T, dot);
  __builtin_amdgcn_sched_barrier(0);
  __builtin_amdgcn_s_barrier();                      // buf1 free everywhere
  __builtin_amdgcn_sched_barrier(0);
  stage_chunk(gsrc + 96, lk[1], wave);   // chunk 3 -> buf1

  // ---- c = 2 ----
  asm volatile("s_waitcnt vmcnt(8)" ::: "memory");   // chunk 2 landed
  __builtin_amdgcn_s_barrier();
  __builtin_amdgcn_sched_barrier(0);
  compute_chunk(&lk[0][t * 32], sw, 2, s2T, dot);

  // ---- c = 3 ----
  asm volatile("s_waitcnt vmcnt(0)" ::: "memory");   // chunk 3 landed
  __builtin_amdgcn_s_barrier();
  __builtin_amdgcn_sched_barrier(0);
  float av[16];
#pragma unroll
  for (int b = 0; b < 16; ++b) av[b] = adj[(size_t)b * 262144 + rid];
  compute_chunk(&lk[1][t * 32], sw, 3, s2T, dot);

  // epilogue: adj * sin(dot), wave reduce, write agg partials
#pragma unroll
  for (int b = 0; b < 16; ++b) {
    float v = av[b] * fast_sin(dot[b]);
#pragma unroll
    for (int off = 32; off > 0; off >>= 1) v += __shfl_down(v, off, 64);
    if ((t & 63) == 0) part[(t >> 6) * 16 + b] = v;
  }
  __syncthreads();
  if (t < 16) {
    float ssum = part[t] + part[16 + t] + part[32 + t] + part[48 + t];
    aggp[half * 8192 + t * 512 + l] = ssum;   // aggp[half][b][l]
  }
}

extern "C" void kernel_launch(void* const* d_in, const int* in_sizes, int n_in,
                              void* d_out, int out_size, void* d_ws, size_t ws_size,
                              hipStream_t stream) {
  const float* y0   = (const float*)d_in[0];  // [16,512]
  const float* bias = (const float*)d_in[1];  // [16,512,1]
  const float* adj  = (const float*)d_in[2];  // [16,512,512]
  const float* k0   = (const float*)d_in[3];  // [128,512,512]
  const float* k1   = (const float*)d_in[4];  // [128,512,128]
  const float* k2   = (const float*)d_in[5];  // [512,512,128]
  float* out = (float*)d_out;                 // [8,16,512] f32

  float* w    = (float*)d_ws;
  float* K0s  = w;               // 65536 floats
  float* K1s  = w + 65536;       // 16384
  float* M    = w + 81920;       // 65536
  float* s2T  = w + 147456;      // 2048  ([128][16] transposed)
  float* ybuf = w + 149504;      // 16384 (2 x 8192, ping-pong)
  float* racc = w + 165888;      // 8192
  float* aggp = w + 174080;      // 16384 (2 halves x [16][512])
  // total: 190464 floats = 762 KB of d_ws

  kPrep1<<<256, 256, 0, stream>>>(k0, K0s);
  kPrep2<<<64, 256, 0, stream>>>(k1, K1s);
  kPrep3<<<256, 256, 0, stream>>>(K0s, K1s, M);

  // init: y = y0, s2T = (M*y0)^T  (step = -1 makes ping-pong write ybuf[0])
  kA<<<64, 256, 0, stream>>>(y0, bias, M, aggp, ybuf, racc, s2T, out, 0, -1);

  for (int step = 0; step < 8; ++step) {
    for (int stage = 1; stage <= 4; ++stage) {
      kB<<<1024, 256, 0, stream>>>(k2, adj, s2T, aggp);
      kA<<<64, 256, 0, stream>>>(y0, bias, M, aggp, ybuf, racc, s2T, out, stage, step);
    }
  }
}

// Round 8
// 4185.538 us; speedup vs baseline: 2.2315x; 2.2315x over previous
//
#include <hip/hip_runtime.h>
#include <hip/hip_bf16.h>

typedef float f32x16 __attribute__((ext_vector_type(16)));

#define DT 0.01f

// sin(x) with Cody-Waite reduction mod pi, accurate to ~2e-7 for |x| < ~6000.
__device__ __forceinline__ float fast_sin(float x) {
  const float INVPI = 0.3183098861837907f;
  float n = rintf(x * INVPI);
  int ni = (int)n;
  float r = fmaf(n, -3.140625f, x);          // n*3.140625 exact for |n| < 2^12
  r = fmaf(n, -9.6765358979e-4f, r);         // pi - 3.140625
  float s = r * r;
  float p = fmaf(s, -2.5052108e-8f, 2.7557319e-6f);
  p = fmaf(s, p, -1.9841270e-4f);
  p = fmaf(s, p, 8.3333333e-3f);
  p = fmaf(s, p, -1.6666667e-1f);
  float res = fmaf(r * s, p, r);             // sin(r), |r| <= pi/2
  return (ni & 1) ? -res : res;              // sin(x) = (-1)^n sin(r)
}

// 4x s_load_dwordx16 from a wave-uniform address + waitcnt, all in one asm
// block. Outputs live in SGPRs; consuming FMAs read them as the free scalar
// operand of v_fmac_f32. Dataflow through the asm outputs orders the FMAs
// after the embedded s_waitcnt.
__device__ __forceinline__ void sload4(const float* p, f32x16& a, f32x16& b,
                                       f32x16& c, f32x16& d) {
  asm volatile(
      "s_load_dwordx16 %0, %4, 0\n\t"
      "s_load_dwordx16 %1, %4, 0x40\n\t"
      "s_load_dwordx16 %2, %4, 0x80\n\t"
      "s_load_dwordx16 %3, %4, 0xc0\n\t"
      "s_waitcnt lgkmcnt(0)"
      : "=s"(a), "=s"(b), "=s"(c), "=s"(d)
      : "s"(p));
}

// K0s[h,j] = sum_m k0[h,m,j]   (k0: [128,512,512])
__global__ __launch_bounds__(256) void kPrep1(const float* __restrict__ k0,
                                              float* __restrict__ K0s) {
  int t = blockIdx.x * 256 + threadIdx.x;     // 65536 threads
  int h = t >> 9, j = t & 511;
  const float* p = k0 + (size_t)h * 262144 + j;
  float s = 0.f;
  for (int m = 0; m < 512; ++m) s += p[(size_t)m * 512];
  K0s[t] = s;
}

// K1s[h,j] = sum_m k1[h,m,j]   (k1: [128,512,128])
__global__ __launch_bounds__(256) void kPrep2(const float* __restrict__ k1,
                                              float* __restrict__ K1s) {
  int t = blockIdx.x * 256 + threadIdx.x;     // 16384 threads
  int h = t >> 7, j = t & 127;
  const float* p = k1 + (size_t)h * 65536 + j;
  float s = 0.f;
  for (int m = 0; m < 512; ++m) s += p[(size_t)m * 128];
  K1s[t] = s;
}

// M[l,j] = sum_h K1s[l,h] * K0s[h,j]   ([128,512] = K1s @ K0s)
__global__ __launch_bounds__(256) void kPrep3(const float* __restrict__ K0s,
                                              const float* __restrict__ K1s,
                                              float* __restrict__ M) {
  int t = blockIdx.x * 256 + threadIdx.x;     // 65536 threads
  int l = t >> 9, j = t & 511;
  float s = 0.f;
#pragma unroll 8
  for (int h = 0; h < 128; ++h) s = fmaf(K1s[l * 128 + h], K0s[h * 512 + j], s);
  M[t] = s;
}

// Kernel A: RK4 bookkeeping + s2T = transpose(M * y_stage).
// Grid 64 WGs x 256: WG = (b = blk>>2, quarter q = blk&3).
// stage: 0 = init (y = y0), 1..4 = RK stages. y ping-pongs on step parity.
__global__ __launch_bounds__(256) void kA(
    const float* __restrict__ y0, const float* __restrict__ bias,
    const float* __restrict__ M, const float* __restrict__ aggp,
    float* __restrict__ ybuf,    // [2][16][512]
    float* __restrict__ racc,    // [16][512]
    float* __restrict__ s2T,     // [128][16]  (j-major, b contiguous)
    float* __restrict__ out,     // [8][16][512]
    int stage, int step) {
  __shared__ float ystage[512];
  __shared__ float red[256];
  const int b = blockIdx.x >> 2, q = blockIdx.x & 3, t = threadIdx.x;
  const float* ycur = ybuf + (step & 1) * 8192;
  float* ynext = ybuf + ((step + 1) & 1) * 8192;

  for (int i = t; i < 512; i += 256) {
    const int idx = b * 512 + i;
    const bool own = (i >> 7) == q;   // this WG owns chunk q of row b
    float ys;
    if (stage == 0) {
      ys = y0[idx];
      if (own) ynext[idx] = ys;       // init writes ybuf[0] (step = -1)
    } else {
      const float r = bias[idx] - (aggp[idx] + aggp[8192 + idx]);
      const float yb = ycur[idx];
      if (stage == 1) {
        ys = fmaf(0.5f * DT, r, yb);
        if (own) racc[idx] = r;
      } else if (stage == 2) {
        ys = fmaf(0.5f * DT, r, yb);
        if (own) racc[idx] = racc[idx] + 2.f * r;
      } else if (stage == 3) {
        ys = fmaf(DT, r, yb);
        if (own) racc[idx] = racc[idx] + 2.f * r;
      } else {  // stage 4: finish step
        ys = yb + (DT / 6.f) * (racc[idx] + r);
        if (own) { ynext[idx] = ys; out[step * 8192 + idx] = ys; }
      }
    }
    ystage[i] = ys;
  }
  __syncthreads();

  // s2[b, l] for l in [q*32, q*32+32): 8 threads per dot, 64 j each.
  const int l = q * 32 + (t >> 3), seg = t & 7;
  const float* Mrow = M + l * 512 + seg * 64;
  float p = 0.f;
#pragma unroll 8
  for (int i = 0; i < 64; ++i) p = fmaf(Mrow[i], ystage[seg * 64 + i], p);
  red[t] = p;
  __syncthreads();
  if (seg == 0) {
    float ssum = 0.f;
#pragma unroll
    for (int k = 0; k < 8; ++k) ssum += red[t + k];
    s2T[l * 16 + b] = ssum;   // transposed: b contiguous per j
  }
}

// Kernel B: one thread per k2 row (l,m). k2 reg-prefetched one chunk ahead
// (R5 structure: prefetch issued after the post-ds_write barrier, flies
// during compute, drained by the NEXT __syncthreads — true overlap with
// plain barrier semantics). __launch_bounds__(256, 2): VGPR cap 256 so the
// ~90-reg live set (pre[8]+dot[16]+av[16]) CANNOT spill — the R5 (cap 64)
// and R6 (cap 128 w/ (256,4)) spills were the only failure. LDS stays the
// proven 0-conflict stride-36 layout, 36 KB -> up to 4 WGs/CU if VGPR<=128.
__global__ __launch_bounds__(256, 2) void kB(
    const float* __restrict__ k2, const float* __restrict__ adj,
    const float* __restrict__ s2T, float* __restrict__ aggp) {
  __shared__ float lk[256 * 36];   // 36 KB, stride 36 floats (0 conflicts)
  __shared__ float part[64];
  const int t = threadIdx.x;
  const int rid0 = blockIdx.x * 256;
  const int rid = rid0 + t;
  const int l = rid0 >> 9;
  const int half = blockIdx.x & 1;

  // prologue: prefetch chunk 0 into registers (coalesced full cache lines)
  float4 pre[8];
#pragma unroll
  for (int k = 0; k < 8; ++k) {
    const int f = k * 256 + t, row = f >> 3, e = f & 7;
    pre[k] = *(const float4*)(k2 + (size_t)(rid0 + row) * 128 + e * 4);
  }

  float dot[16];
#pragma unroll
  for (int b = 0; b < 16; ++b) dot[b] = 0.f;
  float av[16];

#pragma unroll
  for (int c = 0; c < 4; ++c) {
    __syncthreads();   // implicit vmcnt(0): pre(c) arrived; lk free to reuse
#pragma unroll
    for (int k = 0; k < 8; ++k) {
      const int f = k * 256 + t, row = f >> 3, e = f & 7;
      *(float4*)(lk + row * 36 + e * 4) = pre[k];
    }
    __syncthreads();   // lk visible; vmem queue is empty here (cheap drain)
    // issue next chunk's (or adj's) loads, then compute current chunk
    if (c < 3) {
#pragma unroll
      for (int k = 0; k < 8; ++k) {
        const int f = k * 256 + t, row = f >> 3, e = f & 7;
        pre[k] = *(const float4*)(k2 + (size_t)(rid0 + row) * 128 + (c + 1) * 32 + e * 4);
      }
    } else {
#pragma unroll
      for (int b = 0; b < 16; ++b) av[b] = adj[(size_t)b * 262144 + rid];
    }
    const float* myrow = lk + t * 36;
#pragma unroll
    for (int q = 0; q < 8; ++q) {
      const float4 kv = *(const float4*)(myrow + q * 4);
      f32x16 sa, sb, sc, sd;
      sload4(s2T + (c * 32 + q * 4) * 16, sa, sb, sc, sd);
#pragma unroll
      for (int b = 0; b < 16; ++b) dot[b] = fmaf(sa[b], kv.x, dot[b]);
#pragma unroll
      for (int b = 0; b < 16; ++b) dot[b] = fmaf(sb[b], kv.y, dot[b]);
#pragma unroll
      for (int b = 0; b < 16; ++b) dot[b] = fmaf(sc[b], kv.z, dot[b]);
#pragma unroll
      for (int b = 0; b < 16; ++b) dot[b] = fmaf(sd[b], kv.w, dot[b]);
    }
  }

  // epilogue: adj * sin(dot), wave reduce, write agg partials
#pragma unroll
  for (int b = 0; b < 16; ++b) {
    float v = av[b] * fast_sin(dot[b]);
#pragma unroll
    for (int off = 32; off > 0; off >>= 1) v += __shfl_down(v, off, 64);
    if ((t & 63) == 0) part[(t >> 6) * 16 + b] = v;
  }
  __syncthreads();
  if (t < 16) {
    float ssum = part[t] + part[16 + t] + part[32 + t] + part[48 + t];
    aggp[half * 8192 + t * 512 + l] = ssum;   // aggp[half][b][l]
  }
}

extern "C" void kernel_launch(void* const* d_in, const int* in_sizes, int n_in,
                              void* d_out, int out_size, void* d_ws, size_t ws_size,
                              hipStream_t stream) {
  const float* y0   = (const float*)d_in[0];  // [16,512]
  const float* bias = (const float*)d_in[1];  // [16,512,1]
  const float* adj  = (const float*)d_in[2];  // [16,512,512]
  const float* k0   = (const float*)d_in[3];  // [128,512,512]
  const float* k1   = (const float*)d_in[4];  // [128,512,128]
  const float* k2   = (const float*)d_in[5];  // [512,512,128]
  float* out = (float*)d_out;                 // [8,16,512] f32

  float* w    = (float*)d_ws;
  float* K0s  = w;               // 65536 floats
  float* K1s  = w + 65536;       // 16384
  float* M    = w + 81920;       // 65536
  float* s2T  = w + 147456;      // 2048  ([128][16] transposed)
  float* ybuf = w + 149504;      // 16384 (2 x 8192, ping-pong)
  float* racc = w + 165888;      // 8192
  float* aggp = w + 174080;      // 16384 (2 halves x [16][512])
  // total: 190464 floats = 762 KB of d_ws

  kPrep1<<<256, 256, 0, stream>>>(k0, K0s);
  kPrep2<<<64, 256, 0, stream>>>(k1, K1s);
  kPrep3<<<256, 256, 0, stream>>>(K0s, K1s, M);

  // init: y = y0, s2T = (M*y0)^T  (step = -1 makes ping-pong write ybuf[0])
  kA<<<64, 256, 0, stream>>>(y0, bias, M, aggp, ybuf, racc, s2T, out, 0, -1);

  for (int step = 0; step < 8; ++step) {
    for (int stage = 1; stage <= 4; ++stage) {
      kB<<<1024, 256, 0, stream>>>(k2, adj, s2T, aggp);
      kA<<<64, 256, 0, stream>>>(y0, bias, M, aggp, ybuf, racc, s2T, out, stage, step);
    }
  }
}

// Round 9
// 1156.711 us; speedup vs baseline: 8.0745x; 3.6185x over previous
//
#include <hip/hip_runtime.h>
#include <hip/hip_bf16.h>

typedef float f32x16 __attribute__((ext_vector_type(16)));
typedef unsigned int u32;
typedef unsigned short u16;

#define DT 0.01f

// sin(x) with Cody-Waite reduction mod pi, accurate to ~2e-7 for |x| < ~6000.
__device__ __forceinline__ float fast_sin(float x) {
  const float INVPI = 0.3183098861837907f;
  float n = rintf(x * INVPI);
  int ni = (int)n;
  float r = fmaf(n, -3.140625f, x);          // n*3.140625 exact for |n| < 2^12
  r = fmaf(n, -9.6765358979e-4f, r);         // pi - 3.140625
  float s = r * r;
  float p = fmaf(s, -2.5052108e-8f, 2.7557319e-6f);
  p = fmaf(s, p, -1.9841270e-4f);
  p = fmaf(s, p, 8.3333333e-3f);
  p = fmaf(s, p, -1.6666667e-1f);
  float res = fmaf(r * s, p, r);             // sin(r), |r| <= pi/2
  return (ni & 1) ? -res : res;              // sin(x) = (-1)^n sin(r)
}

// 4x s_load_dwordx16 from a wave-uniform address + waitcnt, all in one asm
// block. Outputs live in SGPRs; consuming FMAs read them as the free scalar
// operand of v_fmac_f32.
__device__ __forceinline__ void sload4(const float* p, f32x16& a, f32x16& b,
                                       f32x16& c, f32x16& d) {
  asm volatile(
      "s_load_dwordx16 %0, %4, 0\n\t"
      "s_load_dwordx16 %1, %4, 0x40\n\t"
      "s_load_dwordx16 %2, %4, 0x80\n\t"
      "s_load_dwordx16 %3, %4, 0xc0\n\t"
      "s_waitcnt lgkmcnt(0)"
      : "=s"(a), "=s"(b), "=s"(c), "=s"(d)
      : "s"(p));
}

// K0s[h,j] = sum_m k0[h,m,j]   (k0: [128,512,512])
__global__ __launch_bounds__(256) void kPrep1(const float* __restrict__ k0,
                                              float* __restrict__ K0s) {
  int t = blockIdx.x * 256 + threadIdx.x;     // 65536 threads
  int h = t >> 9, j = t & 511;
  const float* p = k0 + (size_t)h * 262144 + j;
  float s = 0.f;
  for (int m = 0; m < 512; ++m) s += p[(size_t)m * 512];
  K0s[t] = s;
}

// K1s[h,j] = sum_m k1[h,m,j]   (k1: [128,512,128])
__global__ __launch_bounds__(256) void kPrep2(const float* __restrict__ k1,
                                              float* __restrict__ K1s) {
  int t = blockIdx.x * 256 + threadIdx.x;     // 16384 threads
  int h = t >> 7, j = t & 127;
  const float* p = k1 + (size_t)h * 65536 + j;
  float s = 0.f;
  for (int m = 0; m < 512; ++m) s += p[(size_t)m * 128];
  K1s[t] = s;
}

// M[l,j] = sum_h K1s[l,h] * K0s[h,j]   ([128,512] = K1s @ K0s)
__global__ __launch_bounds__(256) void kPrep3(const float* __restrict__ K0s,
                                              const float* __restrict__ K1s,
                                              float* __restrict__ M) {
  int t = blockIdx.x * 256 + threadIdx.x;     // 65536 threads
  int l = t >> 9, j = t & 511;
  float s = 0.f;
#pragma unroll 8
  for (int h = 0; h < 128; ++h) s = fmaf(K1s[l * 128 + h], K0s[h * 512 + j], s);
  M[t] = s;
}

// Per-row int16 quantization of k2: 16 threads per row (8 elems each),
// row max via 16-lane xor-shuffle, q = rint(k2 * 32767/rowmax).
// Grid 16384 x 256 = 16 rows/block, fully coalesced float4 traffic.
__global__ __launch_bounds__(256) void kConvRow(const float* __restrict__ k2,
                                                short* __restrict__ kq,
                                                float* __restrict__ rowinv) {
  const int t = threadIdx.x;
  const int row = blockIdx.x * 16 + (t >> 4);
  const int seg = t & 15;
  const float* src = k2 + (size_t)row * 128 + seg * 8;
  const float4 a = *(const float4*)(src);
  const float4 b = *(const float4*)(src + 4);
  float m = fmaxf(fmaxf(fmaxf(fabsf(a.x), fabsf(a.y)), fmaxf(fabsf(a.z), fabsf(a.w))),
                  fmaxf(fmaxf(fabsf(b.x), fabsf(b.y)), fmaxf(fabsf(b.z), fabsf(b.w))));
#pragma unroll
  for (int off = 8; off > 0; off >>= 1) m = fmaxf(m, __shfl_xor(m, off, 64));
  const float scale = m > 0.f ? 32767.0f / m : 0.f;
  if (seg == 0) rowinv[row] = m > 0.f ? m / 32767.0f : 0.f;
  uint4 o;
  o.x = (u32)(u16)(short)rintf(a.x * scale) | ((u32)(u16)(short)rintf(a.y * scale) << 16);
  o.y = (u32)(u16)(short)rintf(a.z * scale) | ((u32)(u16)(short)rintf(a.w * scale) << 16);
  o.z = (u32)(u16)(short)rintf(b.x * scale) | ((u32)(u16)(short)rintf(b.y * scale) << 16);
  o.w = (u32)(u16)(short)rintf(b.z * scale) | ((u32)(u16)(short)rintf(b.w * scale) << 16);
  *(uint4*)(kq + (size_t)row * 128 + seg * 8) = o;
}

// Kernel A: RK4 bookkeeping + s2T = transpose(M * y_stage).
__global__ __launch_bounds__(256) void kA(
    const float* __restrict__ y0, const float* __restrict__ bias,
    const float* __restrict__ M, const float* __restrict__ aggp,
    float* __restrict__ ybuf,    // [2][16][512]
    float* __restrict__ racc,    // [16][512]
    float* __restrict__ s2T,     // [128][16]  (j-major, b contiguous)
    float* __restrict__ out,     // [8][16][512]
    int stage, int step) {
  __shared__ float ystage[512];
  __shared__ float red[256];
  const int b = blockIdx.x >> 2, q = blockIdx.x & 3, t = threadIdx.x;
  const float* ycur = ybuf + (step & 1) * 8192;
  float* ynext = ybuf + ((step + 1) & 1) * 8192;

  for (int i = t; i < 512; i += 256) {
    const int idx = b * 512 + i;
    const bool own = (i >> 7) == q;
    float ys;
    if (stage == 0) {
      ys = y0[idx];
      if (own) ynext[idx] = ys;
    } else {
      const float r = bias[idx] - (aggp[idx] + aggp[8192 + idx]);
      const float yb = ycur[idx];
      if (stage == 1) {
        ys = fmaf(0.5f * DT, r, yb);
        if (own) racc[idx] = r;
      } else if (stage == 2) {
        ys = fmaf(0.5f * DT, r, yb);
        if (own) racc[idx] = racc[idx] + 2.f * r;
      } else if (stage == 3) {
        ys = fmaf(DT, r, yb);
        if (own) racc[idx] = racc[idx] + 2.f * r;
      } else {
        ys = yb + (DT / 6.f) * (racc[idx] + r);
        if (own) { ynext[idx] = ys; out[step * 8192 + idx] = ys; }
      }
    }
    ystage[i] = ys;
  }
  __syncthreads();

  const int l = q * 32 + (t >> 3), seg = t & 7;
  const float* Mrow = M + l * 512 + seg * 64;
  float p = 0.f;
#pragma unroll 8
  for (int i = 0; i < 64; ++i) p = fmaf(Mrow[i], ystage[seg * 64 + i], p);
  red[t] = p;
  __syncthreads();
  if (seg == 0) {
    float ssum = 0.f;
#pragma unroll
    for (int k = 0; k < 8; ++k) ssum += red[t + k];
    s2T[l * 16 + b] = ssum;
  }
}

// Kernel B (int16 k2): R4's proven serialized-stage structure, half bytes.
// LDS stride 72 shorts = 144B — identical bank pattern to the measured-zero-
// conflict stride-36-float layout (b128 reads at (36*lane+4*q) mod 32).
// dot is accumulated in quantized units; epilogue multiplies by rowinv.
__global__ __launch_bounds__(256) void kBi16(
    const short* __restrict__ kq, const float* __restrict__ adj,
    const float* __restrict__ s2T, const float* __restrict__ rowinv,
    float* __restrict__ aggp) {
  __shared__ short lk[256 * 72];   // 36,864 B
  __shared__ float part[64];
  const int t = threadIdx.x;
  const int rid0 = blockIdx.x * 256;
  const int rid = rid0 + t;
  const int l = rid0 >> 9;
  const int half = blockIdx.x & 1;

  float dot[16];
#pragma unroll
  for (int b = 0; b < 16; ++b) dot[b] = 0.f;

  for (int c = 0; c < 2; ++c) {    // two 64-j chunks
    __syncthreads();
    // stage 256 rows x 64 shorts (128B/row = full cache line), 8 uint4/thread
#pragma unroll
    for (int k = 0; k < 8; ++k) {
      const int f = k * 256 + t, row = f >> 3, e = f & 7;
      const uint4 v = *(const uint4*)(kq + (size_t)(rid0 + row) * 128 + c * 64 + e * 8);
      *(uint4*)(lk + row * 72 + e * 8) = v;
    }
    __syncthreads();
    const short* myrow = lk + t * 72;
#pragma unroll
    for (int qq = 0; qq < 8; ++qq) {
      const uint4 kw = *(const uint4*)(myrow + qq * 8);   // 8 shorts = 8 j
      const int j0 = c * 64 + qq * 8;
      f32x16 sa, sb, sc, sd;
      {
        const float f0 = (float)(short)(kw.x & 0xFFFFu);
        const float f1 = (float)(short)(kw.x >> 16);
        const float f2 = (float)(short)(kw.y & 0xFFFFu);
        const float f3 = (float)(short)(kw.y >> 16);
        sload4(s2T + j0 * 16, sa, sb, sc, sd);
#pragma unroll
        for (int b = 0; b < 16; ++b) dot[b] = fmaf(sa[b], f0, dot[b]);
#pragma unroll
        for (int b = 0; b < 16; ++b) dot[b] = fmaf(sb[b], f1, dot[b]);
#pragma unroll
        for (int b = 0; b < 16; ++b) dot[b] = fmaf(sc[b], f2, dot[b]);
#pragma unroll
        for (int b = 0; b < 16; ++b) dot[b] = fmaf(sd[b], f3, dot[b]);
      }
      {
        const float f4 = (float)(short)(kw.z & 0xFFFFu);
        const float f5 = (float)(short)(kw.z >> 16);
        const float f6 = (float)(short)(kw.w & 0xFFFFu);
        const float f7 = (float)(short)(kw.w >> 16);
        sload4(s2T + (j0 + 4) * 16, sa, sb, sc, sd);
#pragma unroll
        for (int b = 0; b < 16; ++b) dot[b] = fmaf(sa[b], f4, dot[b]);
#pragma unroll
        for (int b = 0; b < 16; ++b) dot[b] = fmaf(sb[b], f5, dot[b]);
#pragma unroll
        for (int b = 0; b < 16; ++b) dot[b] = fmaf(sc[b], f6, dot[b]);
#pragma unroll
        for (int b = 0; b < 16; ++b) dot[b] = fmaf(sd[b], f7, dot[b]);
      }
    }
  }

  const float rinv = rowinv[rid];
#pragma unroll
  for (int b = 0; b < 16; ++b) {
    float v = adj[(size_t)b * 262144 + rid] * fast_sin(dot[b] * rinv);
#pragma unroll
    for (int off = 32; off > 0; off >>= 1) v += __shfl_down(v, off, 64);
    if ((t & 63) == 0) part[(t >> 6) * 16 + b] = v;
  }
  __syncthreads();
  if (t < 16) {
    float ssum = part[t] + part[16 + t] + part[32 + t] + part[48 + t];
    aggp[half * 8192 + t * 512 + l] = ssum;   // aggp[half][b][l]
  }
}

// Kernel B fallback (fp32 k2) — exact R4 body (passing, 34us), used only
// if ws_size can't hold the int16 buffers.
__global__ __launch_bounds__(256) void kBf32(
    const float* __restrict__ k2, const float* __restrict__ adj,
    const float* __restrict__ s2T, float* __restrict__ aggp) {
  __shared__ float lk[256 * 36];
  __shared__ float part[64];
  const int t = threadIdx.x;
  const int rid0 = blockIdx.x * 256;
  const int rid = rid0 + t;
  const int l = rid0 >> 9;
  const int half = blockIdx.x & 1;

  float dot[16];
#pragma unroll
  for (int b = 0; b < 16; ++b) dot[b] = 0.f;

  for (int c = 0; c < 4; ++c) {
    __syncthreads();
#pragma unroll
    for (int k = 0; k < 8; ++k) {
      const int f = k * 256 + t, row = f >> 3, e = f & 7;
      const float4 v = *(const float4*)(k2 + (size_t)(rid0 + row) * 128 + c * 32 + e * 4);
      *(float4*)(lk + row * 36 + e * 4) = v;
    }
    __syncthreads();
    const float* myrow = lk + t * 36;
#pragma unroll
    for (int q = 0; q < 8; ++q) {
      const float4 kv = *(const float4*)(myrow + q * 4);
      f32x16 sa, sb, sc, sd;
      sload4(s2T + (c * 32 + q * 4) * 16, sa, sb, sc, sd);
#pragma unroll
      for (int b = 0; b < 16; ++b) dot[b] = fmaf(sa[b], kv.x, dot[b]);
#pragma unroll
      for (int b = 0; b < 16; ++b) dot[b] = fmaf(sb[b], kv.y, dot[b]);
#pragma unroll
      for (int b = 0; b < 16; ++b) dot[b] = fmaf(sc[b], kv.z, dot[b]);
#pragma unroll
      for (int b = 0; b < 16; ++b) dot[b] = fmaf(sd[b], kv.w, dot[b]);
    }
  }

#pragma unroll
  for (int b = 0; b < 16; ++b) {
    float v = adj[(size_t)b * 262144 + rid] * fast_sin(dot[b]);
#pragma unroll
    for (int off = 32; off > 0; off >>= 1) v += __shfl_down(v, off, 64);
    if ((t & 63) == 0) part[(t >> 6) * 16 + b] = v;
  }
  __syncthreads();
  if (t < 16) {
    float ssum = part[t] + part[16 + t] + part[32 + t] + part[48 + t];
    aggp[half * 8192 + t * 512 + l] = ssum;
  }
}

extern "C" void kernel_launch(void* const* d_in, const int* in_sizes, int n_in,
                              void* d_out, int out_size, void* d_ws, size_t ws_size,
                              hipStream_t stream) {
  const float* y0   = (const float*)d_in[0];  // [16,512]
  const float* bias = (const float*)d_in[1];  // [16,512,1]
  const float* adj  = (const float*)d_in[2];  // [16,512,512]
  const float* k0   = (const float*)d_in[3];  // [128,512,512]
  const float* k1   = (const float*)d_in[4];  // [128,512,128]
  const float* k2   = (const float*)d_in[5];  // [512,512,128]
  float* out = (float*)d_out;                 // [8,16,512] f32

  float* w      = (float*)d_ws;
  float* K0s    = w;               // 65536 floats
  float* K1s    = w + 65536;       // 16384
  float* M      = w + 81920;       // 65536
  float* s2T    = w + 147456;      // 2048  ([128][16] transposed)
  float* ybuf   = w + 149504;      // 16384 (2 x 8192, ping-pong)
  float* racc   = w + 165888;      // 8192
  float* aggp   = w + 174080;      // 16384 (2 halves x [16][512])
  float* rowinv = w + 190464;      // 262144 floats = 1 MB
  short* kq     = (short*)(w + 190464 + 262144);  // 33554432 shorts = 64 MB
  const bool useI16 =
      ws_size >= (size_t)(190464 + 262144) * 4 + (size_t)33554432 * 2;

  kPrep1<<<256, 256, 0, stream>>>(k0, K0s);
  kPrep2<<<64, 256, 0, stream>>>(k1, K1s);
  kPrep3<<<256, 256, 0, stream>>>(K0s, K1s, M);
  if (useI16) kConvRow<<<16384, 256, 0, stream>>>(k2, kq, rowinv);

  kA<<<64, 256, 0, stream>>>(y0, bias, M, aggp, ybuf, racc, s2T, out, 0, -1);

  for (int step = 0; step < 8; ++step) {
    for (int stage = 1; stage <= 4; ++stage) {
      if (useI16)
        kBi16<<<1024, 256, 0, stream>>>(kq, adj, s2T, rowinv, aggp);
      else
        kBf32<<<1024, 256, 0, stream>>>(k2, adj, s2T, aggp);
      kA<<<64, 256, 0, stream>>>(y0, bias, M, aggp, ybuf, racc, s2T, out, stage, step);
    }
  }
}